// Round 11
// baseline (148.478 us; speedup 1.0000x reference)
//
#include <hip/hip_runtime.h>

// HeteroVGAEEncoder: 2-layer GCN on two independent graphs (disease, gene).
// R11: tuning round on the proven R10 pipeline. kBin reshaped for occupancy:
// CHUNK=6400 / 256 thr / 31.3KB LDS -> 5 blocks/CU (20 waves vs 16), dst
// chunk L1-resident for pass 2, finer load balance (1000 blocks). hist is
// reused as sstart post-scan to save LDS. kSort2/kP1F/kP2F byte-identical to
// R10 (122.8us, passed).
//   kBin:   chunk LDS counting sort + per-(chunk,bucket) atomic segment
//           reservation + 16-lane segment copy -> bucket-major record rows.
//   kSort2: per-row node sort (reg-staged), CSR np + dinv + xs epilogue.
//   kP1F:   half-row staged gather -> LDS values -> per-node sums + MLP -> tt.
//   kP2F:   same for layer 2 -> out.
// Floors: ~23us record trips + ~21us gather issue + ~8us index read ~= 55-60.
// Algebraic collapse (verified R1-R10): GCN is linear -> propagate 1 (disease)
// / 2 (gene) scalars; fold dinv[dst] out of edge passes; 32-wide MLP node-wise.

static constexpr int N_NODES = 100000;
static constexpr int N_EDGE  = 3200000;
static constexpr int E4      = N_EDGE / 4;

static constexpr int NPB    = 256;                        // nodes per bucket
static constexpr int NBKT   = (N_NODES + NPB - 1) / NPB;  // 391
static constexpr int NBIN   = 392;                        // hist bins (last: 0)
static constexpr int CHUNK  = 6400;                       // edges per bin-chunk
static constexpr int ABLK   = N_EDGE / CHUNK;             // 500 (exact)
static constexpr int CAP_B  = 9216;  // bucket row capacity (mean 8184, sd 90)
static constexpr unsigned SRC_MASK = 0x1FFFFu;            // 17 bits

static constexpr int HNPB = 128;    // nodes per half-row block (kP1F/kP2F)
static constexpr int HCAP = 4800;   // half-row stage cap (mean 4096, 11 sigma)
static constexpr int LVSZ = HCAP + HCAP / 32 + 4;         // swizzled plane size

__device__ __forceinline__ int swz(int i) { return i + (i >> 5); }

// ============================== fast path =================================

// ---- kBin: chunk counting sort + atomic segment reservation + copy ---------
__global__ __launch_bounds__(256) void kBin(
    const int* __restrict__ ei_d, const int* __restrict__ ei_g,
    unsigned* __restrict__ recB,                  // [2][NBKT][CAP_B]
    int* __restrict__ cur)                        // [2][NBKT], zeroed; ends = bn
{
    __shared__ int hist[NBIN];                    // counts -> sstart after scan
    __shared__ int offs[NBIN];
    __shared__ int gbase[NBIN];
    __shared__ int scanbuf[256];
    __shared__ unsigned stage[CHUNK];             // 25.6 KB; total ~31.3 KB
    const int g = blockIdx.y, blk = blockIdx.x, t = threadIdx.x;
    const int* src = (g ? ei_g : ei_d) + blk * CHUNK;
    const int* dst = (g ? ei_g : ei_d) + N_EDGE + blk * CHUNK;

    for (int i = t; i < NBIN; i += 256) hist[i] = 0;
    __syncthreads();

    // pass 1: bucket histogram (25.6KB dst chunk stays L1-hot for pass 2)
    for (int e = t * 4; e < CHUNK; e += 1024) {
        int4 d4 = *(const int4*)(dst + e);
        atomicAdd(&hist[d4.x >> 8], 1);
        atomicAdd(&hist[d4.y >> 8], 1);
        atomicAdd(&hist[d4.z >> 8], 1);
        atomicAdd(&hist[d4.w >> 8], 1);
    }
    __syncthreads();

    // exclusive scan over NBIN bins (2 bins/thread) + segment reservation
    int c0 = (2 * t < NBIN) ? hist[2 * t] : 0;
    int c1 = (2 * t + 1 < NBIN) ? hist[2 * t + 1] : 0;
    scanbuf[t] = c0 + c1;
    __syncthreads();
    for (int d = 1; d < 256; d <<= 1) {
        int add = (t >= d) ? scanbuf[t - d] : 0;
        __syncthreads();
        scanbuf[t] += add;
        __syncthreads();
    }
    int excl = t ? scanbuf[t - 1] : 0;
    if (2 * t < NBIN) {
        hist[2 * t] = excl;                       // hist becomes sstart
        offs[2 * t] = excl;
        gbase[2 * t] = (2 * t < NBKT && c0 > 0)
                     ? atomicAdd(&cur[g * NBKT + 2 * t], c0) : 0;
    }
    if (2 * t + 1 < NBIN) {
        hist[2 * t + 1] = excl + c0;
        offs[2 * t + 1] = excl + c0;
        gbase[2 * t + 1] = (2 * t + 1 < NBKT && c1 > 0)
                         ? atomicAdd(&cur[g * NBKT + 2 * t + 1], c1) : 0;
    }
    __syncthreads();

    // pass 2: scatter packed records into LDS stage (offs doubles as cursor)
    for (int e = t * 4; e < CHUNK; e += 1024) {
        int4 s4 = *(const int4*)(src + e);
        int4 d4 = *(const int4*)(dst + e);
        int p;
        p = atomicAdd(&offs[d4.x >> 8], 1);
        stage[p] = ((unsigned)(d4.x & 255) << 17) | (unsigned)s4.x;
        p = atomicAdd(&offs[d4.y >> 8], 1);
        stage[p] = ((unsigned)(d4.y & 255) << 17) | (unsigned)s4.y;
        p = atomicAdd(&offs[d4.z >> 8], 1);
        stage[p] = ((unsigned)(d4.z & 255) << 17) | (unsigned)s4.z;
        p = atomicAdd(&offs[d4.w >> 8], 1);
        stage[p] = ((unsigned)(d4.w & 255) << 17) | (unsigned)s4.w;
    }
    __syncthreads();

    // copy each bucket-segment to its reserved global slot (16-lane groups)
    const int grp = t >> 4, ln = t & 15;          // 16 groups
    for (int b = grp; b < NBKT; b += 16) {
        int s0 = hist[b];                         // sstart
        int len = offs[b] - s0;
        if (len == 0) continue;
        int gpos = gbase[b];
        unsigned* dp = recB + ((size_t)(g * NBKT + b)) * CAP_B + gpos;
        for (int i = ln; i < len; i += 16)
            if (gpos + i < CAP_B) dp[i] = stage[s0 + i];
    }
}

// ---- kSort2: sort row by node (reg-staged), emit CSR np + dinv + xs --------
__global__ __launch_bounds__(512) void kSort2(
    unsigned* __restrict__ recB, const int* __restrict__ bn,
    int* __restrict__ np,                         // [2][NBKT][257]
    const float* __restrict__ x_d, const float2* __restrict__ x_g,
    float* __restrict__ dinv_d, float* __restrict__ dinv_g,
    float* __restrict__ xs_d, float2* __restrict__ xs_g)
{
    __shared__ int h2[256];
    __shared__ int sc[512];
    __shared__ int cur2[256];
    __shared__ unsigned stg[CAP_B];
    const int g = blockIdx.y, b = blockIdx.x, t = threadIdx.x;
    if (t < 256) h2[t] = 0;
    __syncthreads();
    const int rowi = g * NBKT + b;
    unsigned* row = recB + (size_t)rowi * CAP_B;
    const int n = min(bn[rowi], CAP_B);

    // register-stage this thread's records (single global read of the row)
    unsigned r[18];                               // ceil(9216/512) = 18
    int cnt = 0;
    for (int i = t; i < n; i += 512) r[cnt++] = row[i];

    for (int j = 0; j < cnt; ++j)
        atomicAdd(&h2[(r[j] >> 17) & 255], 1);
    __syncthreads();

    int c = (t < 256) ? h2[t] : 0;
    sc[t] = c;
    __syncthreads();
    for (int d = 1; d < 256; d <<= 1) {
        int add = (t >= d) ? sc[t - d] : 0;
        __syncthreads();
        sc[t] += add;
        __syncthreads();
    }
    if (t < 256) {
        int excl = sc[t] - c;
        cur2[t] = excl;
        np[rowi * 257 + t] = excl;
    }
    if (t == 0) np[rowi * 257 + 256] = n;
    __syncthreads();

    for (int j = 0; j < cnt; ++j) {
        int p = atomicAdd(&cur2[(r[j] >> 17) & 255], 1);
        stg[p] = r[j];
    }
    __syncthreads();
    for (int i = t; i < n; i += 512) row[i] = stg[i];

    // epilogue: degree is h2[t] -> dinv, pre-scaled features
    if (t < 256) {
        int node = (b << 8) + t;
        if (node < N_NODES) {
            int deg = h2[t];
            float v = deg > 0 ? rsqrtf((float)deg) : 0.0f;
            if (g == 0) {
                dinv_d[node] = v;
                xs_d[node] = x_d[node] * v;
            } else {
                dinv_g[node] = v;
                float2 xg = x_g[node];
                xs_g[node] = make_float2(xg.x * v, xg.y * v);
            }
        }
    }
}

// ---- kP1F: half-row staged gather + per-node LDS sum + MLP -> tt -----------
__global__ __launch_bounds__(512) void kP1F(
    const unsigned* __restrict__ recB, const int* __restrict__ np,
    const float* __restrict__ dinv_d, const float* __restrict__ dinv_g,
    const float* __restrict__ xs_d, const float2* __restrict__ xs_g,
    const float* __restrict__ W1_d, const float* __restrict__ b1_d,
    const float* __restrict__ W2_d,
    const float* __restrict__ W1_g, const float* __restrict__ b1_g,
    const float* __restrict__ W2_g,
    float* __restrict__ tt_d, float* __restrict__ tt_g)
{
    __shared__ float lv[2 * LVSZ];                // ~39.6 KB
    const int g = blockIdx.y;
    const int bkt = blockIdx.x >> 1, h = blockIdx.x & 1, t = threadIdx.x;
    const int rowi = g * NBKT + bkt;
    const int* npr = np + rowi * 257 + h * HNPB;
    const int base = npr[0];
    const int len = min(npr[HNPB] - base, HCAP);
    const unsigned* row = recB + (size_t)rowi * CAP_B + base;

    if (g == 0) {
        int i = t;
        for (; i + 1536 < len; i += 2048) {
            unsigned r0 = row[i], r1 = row[i + 512], r2 = row[i + 1024], r3 = row[i + 1536];
            float v0 = xs_d[r0 & SRC_MASK];
            float v1 = xs_d[r1 & SRC_MASK];
            float v2 = xs_d[r2 & SRC_MASK];
            float v3 = xs_d[r3 & SRC_MASK];
            lv[swz(i)] = v0; lv[swz(i + 512)] = v1;
            lv[swz(i + 1024)] = v2; lv[swz(i + 1536)] = v3;
        }
        for (; i < len; i += 512) lv[swz(i)] = xs_d[row[i] & SRC_MASK];
    } else {
        int i = t;
        for (; i + 1536 < len; i += 2048) {
            unsigned r0 = row[i], r1 = row[i + 512], r2 = row[i + 1024], r3 = row[i + 1536];
            float2 v0 = xs_g[r0 & SRC_MASK];
            float2 v1 = xs_g[r1 & SRC_MASK];
            float2 v2 = xs_g[r2 & SRC_MASK];
            float2 v3 = xs_g[r3 & SRC_MASK];
            lv[swz(i)] = v0.x;        lv[LVSZ + swz(i)] = v0.y;
            lv[swz(i + 512)] = v1.x;  lv[LVSZ + swz(i + 512)] = v1.y;
            lv[swz(i + 1024)] = v2.x; lv[LVSZ + swz(i + 1024)] = v2.y;
            lv[swz(i + 1536)] = v3.x; lv[LVSZ + swz(i + 1536)] = v3.y;
        }
        for (; i < len; i += 512) {
            float2 v = xs_g[row[i] & SRC_MASK];
            lv[swz(i)] = v.x; lv[LVSZ + swz(i)] = v.y;
        }
    }
    __syncthreads();

    const int part = t & 3, tn = t >> 2;          // tn in [0,128)
    const int node = (bkt << 8) + h * HNPB + tn;
    int s = min(npr[tn] - base, len);
    int e = min(npr[tn + 1] - base, len);
    float a0 = 0.0f, a1 = 0.0f;
    if (g == 0) {
        for (int k = s + part; k < e; k += 4) a0 += lv[swz(k)];
    } else {
        for (int k = s + part; k < e; k += 4) {
            a0 += lv[swz(k)];
            a1 += lv[LVSZ + swz(k)];
        }
    }
    a0 += __shfl_xor(a0, 1); a0 += __shfl_xor(a0, 2);
    a1 += __shfl_xor(a1, 1); a1 += __shfl_xor(a1, 2);
    if (part == 0 && node < N_NODES) {
        if (g == 0) {
            float v = dinv_d[node];
            float sf = a0 * v;
            float a = 0.0f;
#pragma unroll
            for (int k = 0; k < 32; ++k)
                a += fmaxf(sf * W1_d[k] + b1_d[k], 0.0f) * W2_d[k];
            tt_d[node] = a * v;
        } else {
            float v = dinv_g[node];
            float sf0 = a0 * v;
            float sf1 = a1 * v;
            float a = 0.0f;
#pragma unroll
            for (int k = 0; k < 32; ++k)
                a += fmaxf(sf0 * W1_g[k] + sf1 * W1_g[32 + k] + b1_g[k], 0.0f) * W2_g[k];
            tt_g[node] = a * v;
        }
    }
}

// ---- kP2F: half-row staged gather (tt) + per-node LDS sum -> out -----------
__global__ __launch_bounds__(512) void kP2F(
    const unsigned* __restrict__ recB, const int* __restrict__ np,
    const float* __restrict__ dinv_d, const float* __restrict__ dinv_g,
    const float* __restrict__ tt_d, const float* __restrict__ tt_g,
    const float* __restrict__ b2_d, const float* __restrict__ b2_g,
    float* __restrict__ out)
{
    __shared__ float lv[LVSZ];                    // ~19.8 KB
    const int g = blockIdx.y;
    const int bkt = blockIdx.x >> 1, h = blockIdx.x & 1, t = threadIdx.x;
    const int rowi = g * NBKT + bkt;
    const int* npr = np + rowi * 257 + h * HNPB;
    const int base = npr[0];
    const int len = min(npr[HNPB] - base, HCAP);
    const unsigned* row = recB + (size_t)rowi * CAP_B + base;
    const float* tt = (g ? tt_g : tt_d);

    int i = t;
    for (; i + 1536 < len; i += 2048) {
        unsigned r0 = row[i], r1 = row[i + 512], r2 = row[i + 1024], r3 = row[i + 1536];
        float v0 = tt[r0 & SRC_MASK];
        float v1 = tt[r1 & SRC_MASK];
        float v2 = tt[r2 & SRC_MASK];
        float v3 = tt[r3 & SRC_MASK];
        lv[swz(i)] = v0; lv[swz(i + 512)] = v1;
        lv[swz(i + 1024)] = v2; lv[swz(i + 1536)] = v3;
    }
    for (; i < len; i += 512) lv[swz(i)] = tt[row[i] & SRC_MASK];
    __syncthreads();

    const int part = t & 3, tn = t >> 2;
    const int node = (bkt << 8) + h * HNPB + tn;
    int s = min(npr[tn] - base, len);
    int e = min(npr[tn + 1] - base, len);
    float a0 = 0.0f;
    for (int k = s + part; k < e; k += 4) a0 += lv[swz(k)];
    a0 += __shfl_xor(a0, 1); a0 += __shfl_xor(a0, 2);
    if (part == 0 && node < N_NODES) {
        float v = (g ? dinv_g : dinv_d)[node];
        float bias = (g ? b2_g : b2_d)[0];
        out[g * N_NODES + node] = a0 * v + bias;
    }
}

// ============================ fallback path (R1) ===========================

__global__ __launch_bounds__(256) void k_deg(
    const int4* __restrict__ dst_d, const int4* __restrict__ dst_g,
    float* __restrict__ deg_d, float* __restrict__ deg_g)
{
    int tid = blockIdx.x * 256 + threadIdx.x;
    int stride = gridDim.x * 256;
    for (int e = tid; e < E4; e += stride) {
        int4 a = dst_d[e];
        int4 b = dst_g[e];
        atomicAdd(&deg_d[a.x], 1.0f); atomicAdd(&deg_d[a.y], 1.0f);
        atomicAdd(&deg_d[a.z], 1.0f); atomicAdd(&deg_d[a.w], 1.0f);
        atomicAdd(&deg_g[b.x], 1.0f); atomicAdd(&deg_g[b.y], 1.0f);
        atomicAdd(&deg_g[b.z], 1.0f); atomicAdd(&deg_g[b.w], 1.0f);
    }
}

__global__ __launch_bounds__(256) void k_dinv(
    float* __restrict__ dinv_d, float* __restrict__ dinv_g,
    const float* __restrict__ x_d, const float2* __restrict__ x_g,
    float* __restrict__ xs_d, float2* __restrict__ xs_g)
{
    int i = blockIdx.x * 256 + threadIdx.x;
    int stride = gridDim.x * 256;
    for (; i < N_NODES; i += stride) {
        float dd = dinv_d[i];
        float vd = dd > 0.0f ? rsqrtf(dd) : 0.0f;
        dinv_d[i] = vd;
        xs_d[i] = x_d[i] * vd;
        float dg = dinv_g[i];
        float vg = dg > 0.0f ? rsqrtf(dg) : 0.0f;
        dinv_g[i] = vg;
        float2 xg = x_g[i];
        xs_g[i] = make_float2(xg.x * vg, xg.y * vg);
    }
}

__global__ __launch_bounds__(256) void k_prop1(
    const int4* __restrict__ src_d, const int4* __restrict__ dst_d,
    const int4* __restrict__ src_g, const int4* __restrict__ dst_g,
    const float* __restrict__ xs_d, const float2* __restrict__ xs_g,
    float* __restrict__ s_d, float2* __restrict__ s_g)
{
    int tid = blockIdx.x * 256 + threadIdx.x;
    int stride = gridDim.x * 256;
    for (int e = tid; e < E4; e += stride) {
        int4 sa = src_d[e]; int4 da = dst_d[e];
        int4 sb = src_g[e]; int4 db = dst_g[e];
        atomicAdd(&s_d[da.x], xs_d[sa.x]);
        atomicAdd(&s_d[da.y], xs_d[sa.y]);
        atomicAdd(&s_d[da.z], xs_d[sa.z]);
        atomicAdd(&s_d[da.w], xs_d[sa.w]);
        float2 g0 = xs_g[sb.x]; float2 g1 = xs_g[sb.y];
        float2 g2 = xs_g[sb.z]; float2 g3 = xs_g[sb.w];
        atomicAdd(&s_g[db.x].x, g0.x); atomicAdd(&s_g[db.x].y, g0.y);
        atomicAdd(&s_g[db.y].x, g1.x); atomicAdd(&s_g[db.y].y, g1.y);
        atomicAdd(&s_g[db.z].x, g2.x); atomicAdd(&s_g[db.z].y, g2.y);
        atomicAdd(&s_g[db.w].x, g3.x); atomicAdd(&s_g[db.w].y, g3.y);
    }
}

__global__ __launch_bounds__(256) void k_node(
    const float* __restrict__ dinv_d, const float* __restrict__ dinv_g,
    float* s_d, float2* s_g,
    const float* __restrict__ W1_d, const float* __restrict__ b1_d,
    const float* __restrict__ W2_d,
    const float* __restrict__ W1_g, const float* __restrict__ b1_g,
    const float* __restrict__ W2_g)
{
    int i = blockIdx.x * 256 + threadIdx.x;
    int stride = gridDim.x * 256;
    for (; i < N_NODES; i += stride) {
        float vd = dinv_d[i];
        float sd = s_d[i] * vd;
        float acc_d = 0.0f;
#pragma unroll
        for (int k = 0; k < 32; ++k)
            acc_d += fmaxf(sd * W1_d[k] + b1_d[k], 0.0f) * W2_d[k];
        s_d[i] = acc_d * vd;
        float vg = dinv_g[i];
        float2 sg = s_g[i];
        float s0 = sg.x * vg;
        float s1 = sg.y * vg;
        float acc_g = 0.0f;
#pragma unroll
        for (int k = 0; k < 32; ++k)
            acc_g += fmaxf(s0 * W1_g[k] + s1 * W1_g[32 + k] + b1_g[k], 0.0f) * W2_g[k];
        s_g[i].x = acc_g * vg;
    }
}

__global__ __launch_bounds__(256) void k_prop2(
    const int4* __restrict__ src_d, const int4* __restrict__ dst_d,
    const int4* __restrict__ src_g, const int4* __restrict__ dst_g,
    const float* __restrict__ tt_d, const float* __restrict__ tt_g2,
    float* __restrict__ out)
{
    int tid = blockIdx.x * 256 + threadIdx.x;
    int stride = gridDim.x * 256;
    for (int e = tid; e < E4; e += stride) {
        int4 sa = src_d[e]; int4 da = dst_d[e];
        int4 sb = src_g[e]; int4 db = dst_g[e];
        atomicAdd(&out[da.x], tt_d[sa.x]);
        atomicAdd(&out[da.y], tt_d[sa.y]);
        atomicAdd(&out[da.z], tt_d[sa.z]);
        atomicAdd(&out[da.w], tt_d[sa.w]);
        atomicAdd(&out[N_NODES + db.x], tt_g2[2 * sb.x]);
        atomicAdd(&out[N_NODES + db.y], tt_g2[2 * sb.y]);
        atomicAdd(&out[N_NODES + db.z], tt_g2[2 * sb.z]);
        atomicAdd(&out[N_NODES + db.w], tt_g2[2 * sb.w]);
    }
}

__global__ __launch_bounds__(256) void k_final(
    float* __restrict__ out,
    const float* __restrict__ dinv_d, const float* __restrict__ dinv_g,
    const float* __restrict__ b2_d, const float* __restrict__ b2_g)
{
    int i = blockIdx.x * 256 + threadIdx.x;
    int stride = gridDim.x * 256;
    float bd = b2_d[0];
    float bg = b2_g[0];
    for (; i < N_NODES; i += stride) {
        out[i] = out[i] * dinv_d[i] + bd;
        out[N_NODES + i] = out[N_NODES + i] * dinv_g[i] + bg;
    }
}

// ================================ launch ===================================

extern "C" void kernel_launch(void* const* d_in, const int* in_sizes, int n_in,
                              void* d_out, int out_size, void* d_ws, size_t ws_size,
                              hipStream_t stream) {
    const float* x_d  = (const float*)d_in[0];
    const float* x_g  = (const float*)d_in[1];
    const int*   ei_d = (const int*)d_in[2];
    const int*   ei_g = (const int*)d_in[3];
    const float* W1_d = (const float*)d_in[4];
    const float* b1_d = (const float*)d_in[5];
    const float* W1_g = (const float*)d_in[6];
    const float* b1_g = (const float*)d_in[7];
    const float* W2_d = (const float*)d_in[8];
    const float* b2_d = (const float*)d_in[9];
    const float* W2_g = (const float*)d_in[10];
    const float* b2_g = (const float*)d_in[11];
    float* out = (float*)d_out;

    // fast-path workspace layout (4B words)
    const size_t RECB_W = (size_t)2 * NBKT * CAP_B;   // 7,206,912
    const size_t NODE_W = (size_t)7 * N_NODES;        //   700,000
    const size_t NP_W   = (size_t)2 * NBKT * 257;     //   200,974
    const size_t CUR_W  = (size_t)2 * NBKT;           //       782
    const size_t need   = RECB_W + NODE_W + NP_W + CUR_W; // ~32.4 MB

    if (ws_size >= need * 4) {
        unsigned* recB = (unsigned*)d_ws;
        float* fws    = (float*)d_ws + RECB_W;
        float* dinv_d = fws;
        float* dinv_g = fws + 1 * N_NODES;
        float* xs_d   = fws + 2 * N_NODES;
        float* xs_g   = fws + 3 * N_NODES;            // [2N] float2
        float* tt_d   = fws + 5 * N_NODES;
        float* tt_g   = fws + 6 * N_NODES;
        int* np  = (int*)d_ws + RECB_W + NODE_W;
        int* cur = np + NP_W;

        hipMemsetAsync(cur, 0, CUR_W * sizeof(int), stream);

        dim3 gBin(ABLK, 2), gS(NBKT, 2), gPF(NBKT * 2, 2);
        kBin  <<<gBin, 256, 0, stream>>>(ei_d, ei_g, recB, cur);
        kSort2<<<gS, 512, 0, stream>>>(recB, cur, np, x_d, (const float2*)x_g,
                                       dinv_d, dinv_g, xs_d, (float2*)xs_g);
        kP1F  <<<gPF, 512, 0, stream>>>(recB, np, dinv_d, dinv_g,
                                        xs_d, (const float2*)xs_g,
                                        W1_d, b1_d, W2_d, W1_g, b1_g, W2_g,
                                        tt_d, tt_g);
        kP2F  <<<gPF, 512, 0, stream>>>(recB, np, dinv_d, dinv_g, tt_d, tt_g,
                                        b2_d, b2_g, out);
        return;
    }

    // fallback: R1 scattered-atomic path (correct, slower)
    const int* src_d = ei_d;
    const int* dst_d = ei_d + N_EDGE;
    const int* src_g = ei_g;
    const int* dst_g = ei_g + N_EDGE;

    float* ws     = (float*)d_ws;
    float* dinv_d = ws;
    float* dinv_g = ws + 1 * N_NODES;
    float* s_d    = ws + 2 * N_NODES;
    float* s_g    = ws + 3 * N_NODES;
    float* xs_d   = ws + 5 * N_NODES;
    float* xs_g   = ws + 6 * N_NODES;

    hipMemsetAsync(ws, 0, (size_t)5 * N_NODES * sizeof(float), stream);
    hipMemsetAsync(d_out, 0, (size_t)2 * N_NODES * sizeof(float), stream);

    const int EB = (E4 + 255) / 256;
    const int NB = (N_NODES + 255) / 256;

    k_deg<<<EB, 256, 0, stream>>>((const int4*)dst_d, (const int4*)dst_g,
                                  dinv_d, dinv_g);
    k_dinv<<<NB, 256, 0, stream>>>(dinv_d, dinv_g, x_d, (const float2*)x_g,
                                   xs_d, (float2*)xs_g);
    k_prop1<<<EB, 256, 0, stream>>>((const int4*)src_d, (const int4*)dst_d,
                                    (const int4*)src_g, (const int4*)dst_g,
                                    xs_d, (const float2*)xs_g,
                                    s_d, (float2*)s_g);
    k_node<<<NB, 256, 0, stream>>>(dinv_d, dinv_g, s_d, (float2*)s_g,
                                   W1_d, b1_d, W2_d, W1_g, b1_g, W2_g);
    k_prop2<<<EB, 256, 0, stream>>>((const int4*)src_d, (const int4*)dst_d,
                                    (const int4*)src_g, (const int4*)dst_g,
                                    s_d, s_g, out);
    k_final<<<NB, 256, 0, stream>>>(out, dinv_d, dinv_g, b2_d, b2_g);
}

// Round 12
// 122.031 us; speedup vs baseline: 1.2167x; 1.2167x over previous
//
#include <hip/hip_runtime.h>

// HeteroVGAEEncoder: 2-layer GCN on two independent graphs (disease, gene).
// R12: exact restore of R10 (122.8us, best). R11's kBin reshape (smaller
// chunks / 256thr) regressed 30->56us: per-block fixed cost (scan + 391-
// bucket copy loop) and halved segment length (64B partial-line writes)
// dominate over wave count. Fewer, bigger chunks win for the LDS sort.
// Pipeline:
//   kBin:  per-chunk LDS counting sort (CHUNK2=12800, 512thr) + per-(chunk,
//          bucket) global-atomic segment reservation + 16-lane segment copy.
//   kSort2: per-row node sort (records register-staged, single row read),
//          CSR np + dinv + xs epilogue.
//   kP1F/kP2F: half-row staged-gather prop kernels (R8-proven).
// Known walls (R5-R11 evidence): kP1F/kP2F are divergent-gather issue-rate
// bound (cache-invariant duration at max occupancy); kBin/kSort2 at their
// LDS-sort floors; grid.sync() costs ~100x a launch (R9).
// Algebraic collapse (verified R1-R10): GCN is linear -> propagate 1 (disease)
// / 2 (gene) scalars; fold dinv[dst] out of edge passes; 32-wide MLP node-wise.

static constexpr int N_NODES = 100000;
static constexpr int N_EDGE  = 3200000;
static constexpr int E4      = N_EDGE / 4;

static constexpr int NPB    = 256;                        // nodes per bucket
static constexpr int NBKT   = (N_NODES + NPB - 1) / NPB;  // 391
static constexpr int NBIN   = 392;                        // hist bins (last: 0)
static constexpr int CHUNK2 = 12800;                      // edges per bin-chunk
static constexpr int ABLK2  = N_EDGE / CHUNK2;            // 250 (exact)
static constexpr int CAP_B  = 9216;  // bucket row capacity (mean 8184, sd 90)
static constexpr unsigned SRC_MASK = 0x1FFFFu;            // 17 bits

static constexpr int HNPB = 128;    // nodes per half-row block (kP1F/kP2F)
static constexpr int HCAP = 4800;   // half-row stage cap (mean 4096, 11 sigma)
static constexpr int LVSZ = HCAP + HCAP / 32 + 4;         // swizzled plane size

__device__ __forceinline__ int swz(int i) { return i + (i >> 5); }

// ============================== fast path =================================

// ---- kBin: chunk counting sort + atomic segment reservation + copy ---------
__global__ __launch_bounds__(512) void kBin(
    const int* __restrict__ ei_d, const int* __restrict__ ei_g,
    unsigned* __restrict__ recB,                  // [2][NBKT][CAP_B]
    int* __restrict__ cur)                        // [2][NBKT], zeroed; ends = bn
{
    __shared__ int hist[NBIN];
    __shared__ int sstart[NBIN];
    __shared__ int offs[NBIN];
    __shared__ int gbase[NBIN];
    __shared__ int scanbuf[512];
    __shared__ unsigned stage[CHUNK2];            // 51.2 KB; total ~59.5 KB
    const int g = blockIdx.y, blk = blockIdx.x, t = threadIdx.x;
    const int* src = (g ? ei_g : ei_d) + blk * CHUNK2;
    const int* dst = (g ? ei_g : ei_d) + N_EDGE + blk * CHUNK2;

    for (int i = t; i < NBIN; i += 512) hist[i] = 0;
    __syncthreads();

    // pass 1: bucket histogram (dst stays L1/L2-hot for pass 2)
    for (int e = t * 4; e < CHUNK2; e += 2048) {
        int4 d4 = *(const int4*)(dst + e);
        atomicAdd(&hist[d4.x >> 8], 1);
        atomicAdd(&hist[d4.y >> 8], 1);
        atomicAdd(&hist[d4.z >> 8], 1);
        atomicAdd(&hist[d4.w >> 8], 1);
    }
    __syncthreads();

    // exclusive scan over NBIN bins (one bin per thread, Hillis-Steele 512)
    int c = (t < NBIN) ? hist[t] : 0;
    scanbuf[t] = c;
    __syncthreads();
    for (int d = 1; d < 512; d <<= 1) {
        int add = (t >= d) ? scanbuf[t - d] : 0;
        __syncthreads();
        scanbuf[t] += add;
        __syncthreads();
    }
    int excl = scanbuf[t] - c;
    if (t < NBIN) {
        sstart[t] = excl;
        offs[t] = excl;
        // reserve this chunk's segment in the bucket row (one atomic)
        gbase[t] = (t < NBKT && c > 0) ? atomicAdd(&cur[g * NBKT + t], c) : 0;
    }
    __syncthreads();

    // pass 2: scatter packed records into LDS stage (offs doubles as cursor)
    for (int e = t * 4; e < CHUNK2; e += 2048) {
        int4 s4 = *(const int4*)(src + e);
        int4 d4 = *(const int4*)(dst + e);
        int p;
        p = atomicAdd(&offs[d4.x >> 8], 1);
        stage[p] = ((unsigned)(d4.x & 255) << 17) | (unsigned)s4.x;
        p = atomicAdd(&offs[d4.y >> 8], 1);
        stage[p] = ((unsigned)(d4.y & 255) << 17) | (unsigned)s4.y;
        p = atomicAdd(&offs[d4.z >> 8], 1);
        stage[p] = ((unsigned)(d4.z & 255) << 17) | (unsigned)s4.z;
        p = atomicAdd(&offs[d4.w >> 8], 1);
        stage[p] = ((unsigned)(d4.w & 255) << 17) | (unsigned)s4.w;
    }
    __syncthreads();

    // copy each bucket-segment to its reserved global slot (16-lane groups)
    const int grp = t >> 4, ln = t & 15;          // 32 groups
    for (int b = grp; b < NBKT; b += 32) {
        int s0 = sstart[b];
        int len = offs[b] - s0;
        if (len == 0) continue;
        int gpos = gbase[b];
        unsigned* dp = recB + ((size_t)(g * NBKT + b)) * CAP_B + gpos;
        for (int i = ln; i < len; i += 16)
            if (gpos + i < CAP_B) dp[i] = stage[s0 + i];
    }
}

// ---- kSort2: sort row by node (reg-staged), emit CSR np + dinv + xs --------
__global__ __launch_bounds__(512) void kSort2(
    unsigned* __restrict__ recB, const int* __restrict__ bn,
    int* __restrict__ np,                         // [2][NBKT][257]
    const float* __restrict__ x_d, const float2* __restrict__ x_g,
    float* __restrict__ dinv_d, float* __restrict__ dinv_g,
    float* __restrict__ xs_d, float2* __restrict__ xs_g)
{
    __shared__ int h2[256];
    __shared__ int sc[512];
    __shared__ int cur2[256];
    __shared__ unsigned stg[CAP_B];
    const int g = blockIdx.y, b = blockIdx.x, t = threadIdx.x;
    if (t < 256) h2[t] = 0;
    __syncthreads();
    const int rowi = g * NBKT + b;
    unsigned* row = recB + (size_t)rowi * CAP_B;
    const int n = min(bn[rowi], CAP_B);

    // register-stage this thread's records (single global read of the row)
    unsigned r[18];                               // ceil(9216/512) = 18
    int cnt = 0;
    for (int i = t; i < n; i += 512) r[cnt++] = row[i];

    for (int j = 0; j < cnt; ++j)
        atomicAdd(&h2[(r[j] >> 17) & 255], 1);
    __syncthreads();

    int c = (t < 256) ? h2[t] : 0;
    sc[t] = c;
    __syncthreads();
    for (int d = 1; d < 256; d <<= 1) {
        int add = (t >= d) ? sc[t - d] : 0;
        __syncthreads();
        sc[t] += add;
        __syncthreads();
    }
    if (t < 256) {
        int excl = sc[t] - c;
        cur2[t] = excl;
        np[rowi * 257 + t] = excl;
    }
    if (t == 0) np[rowi * 257 + 256] = n;
    __syncthreads();

    for (int j = 0; j < cnt; ++j) {
        int p = atomicAdd(&cur2[(r[j] >> 17) & 255], 1);
        stg[p] = r[j];
    }
    __syncthreads();
    for (int i = t; i < n; i += 512) row[i] = stg[i];

    // epilogue: degree is h2[t] -> dinv, pre-scaled features
    if (t < 256) {
        int node = (b << 8) + t;
        if (node < N_NODES) {
            int deg = h2[t];
            float v = deg > 0 ? rsqrtf((float)deg) : 0.0f;
            if (g == 0) {
                dinv_d[node] = v;
                xs_d[node] = x_d[node] * v;
            } else {
                dinv_g[node] = v;
                float2 xg = x_g[node];
                xs_g[node] = make_float2(xg.x * v, xg.y * v);
            }
        }
    }
}

// ---- kP1F: half-row staged gather + per-node LDS sum + MLP -> tt -----------
__global__ __launch_bounds__(512) void kP1F(
    const unsigned* __restrict__ recB, const int* __restrict__ np,
    const float* __restrict__ dinv_d, const float* __restrict__ dinv_g,
    const float* __restrict__ xs_d, const float2* __restrict__ xs_g,
    const float* __restrict__ W1_d, const float* __restrict__ b1_d,
    const float* __restrict__ W2_d,
    const float* __restrict__ W1_g, const float* __restrict__ b1_g,
    const float* __restrict__ W2_g,
    float* __restrict__ tt_d, float* __restrict__ tt_g)
{
    __shared__ float lv[2 * LVSZ];                // ~39.6 KB
    const int g = blockIdx.y;
    const int bkt = blockIdx.x >> 1, h = blockIdx.x & 1, t = threadIdx.x;
    const int rowi = g * NBKT + bkt;
    const int* npr = np + rowi * 257 + h * HNPB;
    const int base = npr[0];
    const int len = min(npr[HNPB] - base, HCAP);
    const unsigned* row = recB + (size_t)rowi * CAP_B + base;

    if (g == 0) {
        int i = t;
        for (; i + 1536 < len; i += 2048) {
            unsigned r0 = row[i], r1 = row[i + 512], r2 = row[i + 1024], r3 = row[i + 1536];
            float v0 = xs_d[r0 & SRC_MASK];
            float v1 = xs_d[r1 & SRC_MASK];
            float v2 = xs_d[r2 & SRC_MASK];
            float v3 = xs_d[r3 & SRC_MASK];
            lv[swz(i)] = v0; lv[swz(i + 512)] = v1;
            lv[swz(i + 1024)] = v2; lv[swz(i + 1536)] = v3;
        }
        for (; i < len; i += 512) lv[swz(i)] = xs_d[row[i] & SRC_MASK];
    } else {
        int i = t;
        for (; i + 1536 < len; i += 2048) {
            unsigned r0 = row[i], r1 = row[i + 512], r2 = row[i + 1024], r3 = row[i + 1536];
            float2 v0 = xs_g[r0 & SRC_MASK];
            float2 v1 = xs_g[r1 & SRC_MASK];
            float2 v2 = xs_g[r2 & SRC_MASK];
            float2 v3 = xs_g[r3 & SRC_MASK];
            lv[swz(i)] = v0.x;        lv[LVSZ + swz(i)] = v0.y;
            lv[swz(i + 512)] = v1.x;  lv[LVSZ + swz(i + 512)] = v1.y;
            lv[swz(i + 1024)] = v2.x; lv[LVSZ + swz(i + 1024)] = v2.y;
            lv[swz(i + 1536)] = v3.x; lv[LVSZ + swz(i + 1536)] = v3.y;
        }
        for (; i < len; i += 512) {
            float2 v = xs_g[row[i] & SRC_MASK];
            lv[swz(i)] = v.x; lv[LVSZ + swz(i)] = v.y;
        }
    }
    __syncthreads();

    const int part = t & 3, tn = t >> 2;          // tn in [0,128)
    const int node = (bkt << 8) + h * HNPB + tn;
    int s = min(npr[tn] - base, len);
    int e = min(npr[tn + 1] - base, len);
    float a0 = 0.0f, a1 = 0.0f;
    if (g == 0) {
        for (int k = s + part; k < e; k += 4) a0 += lv[swz(k)];
    } else {
        for (int k = s + part; k < e; k += 4) {
            a0 += lv[swz(k)];
            a1 += lv[LVSZ + swz(k)];
        }
    }
    a0 += __shfl_xor(a0, 1); a0 += __shfl_xor(a0, 2);
    a1 += __shfl_xor(a1, 1); a1 += __shfl_xor(a1, 2);
    if (part == 0 && node < N_NODES) {
        if (g == 0) {
            float v = dinv_d[node];
            float sf = a0 * v;
            float a = 0.0f;
#pragma unroll
            for (int k = 0; k < 32; ++k)
                a += fmaxf(sf * W1_d[k] + b1_d[k], 0.0f) * W2_d[k];
            tt_d[node] = a * v;
        } else {
            float v = dinv_g[node];
            float sf0 = a0 * v;
            float sf1 = a1 * v;
            float a = 0.0f;
#pragma unroll
            for (int k = 0; k < 32; ++k)
                a += fmaxf(sf0 * W1_g[k] + sf1 * W1_g[32 + k] + b1_g[k], 0.0f) * W2_g[k];
            tt_g[node] = a * v;
        }
    }
}

// ---- kP2F: half-row staged gather (tt) + per-node LDS sum -> out -----------
__global__ __launch_bounds__(512) void kP2F(
    const unsigned* __restrict__ recB, const int* __restrict__ np,
    const float* __restrict__ dinv_d, const float* __restrict__ dinv_g,
    const float* __restrict__ tt_d, const float* __restrict__ tt_g,
    const float* __restrict__ b2_d, const float* __restrict__ b2_g,
    float* __restrict__ out)
{
    __shared__ float lv[LVSZ];                    // ~19.8 KB
    const int g = blockIdx.y;
    const int bkt = blockIdx.x >> 1, h = blockIdx.x & 1, t = threadIdx.x;
    const int rowi = g * NBKT + bkt;
    const int* npr = np + rowi * 257 + h * HNPB;
    const int base = npr[0];
    const int len = min(npr[HNPB] - base, HCAP);
    const unsigned* row = recB + (size_t)rowi * CAP_B + base;
    const float* tt = (g ? tt_g : tt_d);

    int i = t;
    for (; i + 1536 < len; i += 2048) {
        unsigned r0 = row[i], r1 = row[i + 512], r2 = row[i + 1024], r3 = row[i + 1536];
        float v0 = tt[r0 & SRC_MASK];
        float v1 = tt[r1 & SRC_MASK];
        float v2 = tt[r2 & SRC_MASK];
        float v3 = tt[r3 & SRC_MASK];
        lv[swz(i)] = v0; lv[swz(i + 512)] = v1;
        lv[swz(i + 1024)] = v2; lv[swz(i + 1536)] = v3;
    }
    for (; i < len; i += 512) lv[swz(i)] = tt[row[i] & SRC_MASK];
    __syncthreads();

    const int part = t & 3, tn = t >> 2;
    const int node = (bkt << 8) + h * HNPB + tn;
    int s = min(npr[tn] - base, len);
    int e = min(npr[tn + 1] - base, len);
    float a0 = 0.0f;
    for (int k = s + part; k < e; k += 4) a0 += lv[swz(k)];
    a0 += __shfl_xor(a0, 1); a0 += __shfl_xor(a0, 2);
    if (part == 0 && node < N_NODES) {
        float v = (g ? dinv_g : dinv_d)[node];
        float bias = (g ? b2_g : b2_d)[0];
        out[g * N_NODES + node] = a0 * v + bias;
    }
}

// ============================ fallback path (R1) ===========================

__global__ __launch_bounds__(256) void k_deg(
    const int4* __restrict__ dst_d, const int4* __restrict__ dst_g,
    float* __restrict__ deg_d, float* __restrict__ deg_g)
{
    int tid = blockIdx.x * 256 + threadIdx.x;
    int stride = gridDim.x * 256;
    for (int e = tid; e < E4; e += stride) {
        int4 a = dst_d[e];
        int4 b = dst_g[e];
        atomicAdd(&deg_d[a.x], 1.0f); atomicAdd(&deg_d[a.y], 1.0f);
        atomicAdd(&deg_d[a.z], 1.0f); atomicAdd(&deg_d[a.w], 1.0f);
        atomicAdd(&deg_g[b.x], 1.0f); atomicAdd(&deg_g[b.y], 1.0f);
        atomicAdd(&deg_g[b.z], 1.0f); atomicAdd(&deg_g[b.w], 1.0f);
    }
}

__global__ __launch_bounds__(256) void k_dinv(
    float* __restrict__ dinv_d, float* __restrict__ dinv_g,
    const float* __restrict__ x_d, const float2* __restrict__ x_g,
    float* __restrict__ xs_d, float2* __restrict__ xs_g)
{
    int i = blockIdx.x * 256 + threadIdx.x;
    int stride = gridDim.x * 256;
    for (; i < N_NODES; i += stride) {
        float dd = dinv_d[i];
        float vd = dd > 0.0f ? rsqrtf(dd) : 0.0f;
        dinv_d[i] = vd;
        xs_d[i] = x_d[i] * vd;
        float dg = dinv_g[i];
        float vg = dg > 0.0f ? rsqrtf(dg) : 0.0f;
        dinv_g[i] = vg;
        float2 xg = x_g[i];
        xs_g[i] = make_float2(xg.x * vg, xg.y * vg);
    }
}

__global__ __launch_bounds__(256) void k_prop1(
    const int4* __restrict__ src_d, const int4* __restrict__ dst_d,
    const int4* __restrict__ src_g, const int4* __restrict__ dst_g,
    const float* __restrict__ xs_d, const float2* __restrict__ xs_g,
    float* __restrict__ s_d, float2* __restrict__ s_g)
{
    int tid = blockIdx.x * 256 + threadIdx.x;
    int stride = gridDim.x * 256;
    for (int e = tid; e < E4; e += stride) {
        int4 sa = src_d[e]; int4 da = dst_d[e];
        int4 sb = src_g[e]; int4 db = dst_g[e];
        atomicAdd(&s_d[da.x], xs_d[sa.x]);
        atomicAdd(&s_d[da.y], xs_d[sa.y]);
        atomicAdd(&s_d[da.z], xs_d[sa.z]);
        atomicAdd(&s_d[da.w], xs_d[sa.w]);
        float2 g0 = xs_g[sb.x]; float2 g1 = xs_g[sb.y];
        float2 g2 = xs_g[sb.z]; float2 g3 = xs_g[sb.w];
        atomicAdd(&s_g[db.x].x, g0.x); atomicAdd(&s_g[db.x].y, g0.y);
        atomicAdd(&s_g[db.y].x, g1.x); atomicAdd(&s_g[db.y].y, g1.y);
        atomicAdd(&s_g[db.z].x, g2.x); atomicAdd(&s_g[db.z].y, g2.y);
        atomicAdd(&s_g[db.w].x, g3.x); atomicAdd(&s_g[db.w].y, g3.y);
    }
}

__global__ __launch_bounds__(256) void k_node(
    const float* __restrict__ dinv_d, const float* __restrict__ dinv_g,
    float* s_d, float2* s_g,
    const float* __restrict__ W1_d, const float* __restrict__ b1_d,
    const float* __restrict__ W2_d,
    const float* __restrict__ W1_g, const float* __restrict__ b1_g,
    const float* __restrict__ W2_g)
{
    int i = blockIdx.x * 256 + threadIdx.x;
    int stride = gridDim.x * 256;
    for (; i < N_NODES; i += stride) {
        float vd = dinv_d[i];
        float sd = s_d[i] * vd;
        float acc_d = 0.0f;
#pragma unroll
        for (int k = 0; k < 32; ++k)
            acc_d += fmaxf(sd * W1_d[k] + b1_d[k], 0.0f) * W2_d[k];
        s_d[i] = acc_d * vd;
        float vg = dinv_g[i];
        float2 sg = s_g[i];
        float s0 = sg.x * vg;
        float s1 = sg.y * vg;
        float acc_g = 0.0f;
#pragma unroll
        for (int k = 0; k < 32; ++k)
            acc_g += fmaxf(s0 * W1_g[k] + s1 * W1_g[32 + k] + b1_g[k], 0.0f) * W2_g[k];
        s_g[i].x = acc_g * vg;
    }
}

__global__ __launch_bounds__(256) void k_prop2(
    const int4* __restrict__ src_d, const int4* __restrict__ dst_d,
    const int4* __restrict__ src_g, const int4* __restrict__ dst_g,
    const float* __restrict__ tt_d, const float* __restrict__ tt_g2,
    float* __restrict__ out)
{
    int tid = blockIdx.x * 256 + threadIdx.x;
    int stride = gridDim.x * 256;
    for (int e = tid; e < E4; e += stride) {
        int4 sa = src_d[e]; int4 da = dst_d[e];
        int4 sb = src_g[e]; int4 db = dst_g[e];
        atomicAdd(&out[da.x], tt_d[sa.x]);
        atomicAdd(&out[da.y], tt_d[sa.y]);
        atomicAdd(&out[da.z], tt_d[sa.z]);
        atomicAdd(&out[da.w], tt_d[sa.w]);
        atomicAdd(&out[N_NODES + db.x], tt_g2[2 * sb.x]);
        atomicAdd(&out[N_NODES + db.y], tt_g2[2 * sb.y]);
        atomicAdd(&out[N_NODES + db.z], tt_g2[2 * sb.z]);
        atomicAdd(&out[N_NODES + db.w], tt_g2[2 * sb.w]);
    }
}

__global__ __launch_bounds__(256) void k_final(
    float* __restrict__ out,
    const float* __restrict__ dinv_d, const float* __restrict__ dinv_g,
    const float* __restrict__ b2_d, const float* __restrict__ b2_g)
{
    int i = blockIdx.x * 256 + threadIdx.x;
    int stride = gridDim.x * 256;
    float bd = b2_d[0];
    float bg = b2_g[0];
    for (; i < N_NODES; i += stride) {
        out[i] = out[i] * dinv_d[i] + bd;
        out[N_NODES + i] = out[N_NODES + i] * dinv_g[i] + bg;
    }
}

// ================================ launch ===================================

extern "C" void kernel_launch(void* const* d_in, const int* in_sizes, int n_in,
                              void* d_out, int out_size, void* d_ws, size_t ws_size,
                              hipStream_t stream) {
    const float* x_d  = (const float*)d_in[0];
    const float* x_g  = (const float*)d_in[1];
    const int*   ei_d = (const int*)d_in[2];
    const int*   ei_g = (const int*)d_in[3];
    const float* W1_d = (const float*)d_in[4];
    const float* b1_d = (const float*)d_in[5];
    const float* W1_g = (const float*)d_in[6];
    const float* b1_g = (const float*)d_in[7];
    const float* W2_d = (const float*)d_in[8];
    const float* b2_d = (const float*)d_in[9];
    const float* W2_g = (const float*)d_in[10];
    const float* b2_g = (const float*)d_in[11];
    float* out = (float*)d_out;

    // fast-path workspace layout (4B words)
    const size_t RECB_W = (size_t)2 * NBKT * CAP_B;   // 7,206,912
    const size_t NODE_W = (size_t)7 * N_NODES;        //   700,000
    const size_t NP_W   = (size_t)2 * NBKT * 257;     //   200,974
    const size_t CUR_W  = (size_t)2 * NBKT;           //       782
    const size_t need   = RECB_W + NODE_W + NP_W + CUR_W; // ~32.4 MB

    if (ws_size >= need * 4) {
        unsigned* recB = (unsigned*)d_ws;
        float* fws    = (float*)d_ws + RECB_W;
        float* dinv_d = fws;
        float* dinv_g = fws + 1 * N_NODES;
        float* xs_d   = fws + 2 * N_NODES;
        float* xs_g   = fws + 3 * N_NODES;            // [2N] float2
        float* tt_d   = fws + 5 * N_NODES;
        float* tt_g   = fws + 6 * N_NODES;
        int* np  = (int*)d_ws + RECB_W + NODE_W;
        int* cur = np + NP_W;

        hipMemsetAsync(cur, 0, CUR_W * sizeof(int), stream);

        dim3 gBin(ABLK2, 2), gS(NBKT, 2), gPF(NBKT * 2, 2);
        kBin  <<<gBin, 512, 0, stream>>>(ei_d, ei_g, recB, cur);
        kSort2<<<gS, 512, 0, stream>>>(recB, cur, np, x_d, (const float2*)x_g,
                                       dinv_d, dinv_g, xs_d, (float2*)xs_g);
        kP1F  <<<gPF, 512, 0, stream>>>(recB, np, dinv_d, dinv_g,
                                        xs_d, (const float2*)xs_g,
                                        W1_d, b1_d, W2_d, W1_g, b1_g, W2_g,
                                        tt_d, tt_g);
        kP2F  <<<gPF, 512, 0, stream>>>(recB, np, dinv_d, dinv_g, tt_d, tt_g,
                                        b2_d, b2_g, out);
        return;
    }

    // fallback: R1 scattered-atomic path (correct, slower)
    const int* src_d = ei_d;
    const int* dst_d = ei_d + N_EDGE;
    const int* src_g = ei_g;
    const int* dst_g = ei_g + N_EDGE;

    float* ws     = (float*)d_ws;
    float* dinv_d = ws;
    float* dinv_g = ws + 1 * N_NODES;
    float* s_d    = ws + 2 * N_NODES;
    float* s_g    = ws + 3 * N_NODES;
    float* xs_d   = ws + 5 * N_NODES;
    float* xs_g   = ws + 6 * N_NODES;

    hipMemsetAsync(ws, 0, (size_t)5 * N_NODES * sizeof(float), stream);
    hipMemsetAsync(d_out, 0, (size_t)2 * N_NODES * sizeof(float), stream);

    const int EB = (E4 + 255) / 256;
    const int NB = (N_NODES + 255) / 256;

    k_deg<<<EB, 256, 0, stream>>>((const int4*)dst_d, (const int4*)dst_g,
                                  dinv_d, dinv_g);
    k_dinv<<<NB, 256, 0, stream>>>(dinv_d, dinv_g, x_d, (const float2*)x_g,
                                   xs_d, (float2*)xs_g);
    k_prop1<<<EB, 256, 0, stream>>>((const int4*)src_d, (const int4*)dst_d,
                                    (const int4*)src_g, (const int4*)dst_g,
                                    xs_d, (const float2*)xs_g,
                                    s_d, (float2*)s_g);
    k_node<<<NB, 256, 0, stream>>>(dinv_d, dinv_g, s_d, (float2*)s_g,
                                   W1_d, b1_d, W2_d, W1_g, b1_g, W2_g);
    k_prop2<<<EB, 256, 0, stream>>>((const int4*)src_d, (const int4*)dst_d,
                                    (const int4*)src_g, (const int4*)dst_g,
                                    s_d, s_g, out);
    k_final<<<NB, 256, 0, stream>>>(out, dinv_d, dinv_g, b2_d, b2_g);
}